// Round 5
// baseline (727.403 us; speedup 1.0000x reference)
//
#include <hip/hip_runtime.h>
#include <math.h>

#define VSEG 50000
#define CH 32
#define KIN 10
#define NB_STATS 512
#define STATS_B 512
#define SCAN_B 256
#define NBLK_SCAN ((VSEG + SCAN_B - 1) / SCAN_B)   // 196

// ---------------------------- init workspace --------------------------------
__global__ __launch_bounds__(256) void init_cnt_k(unsigned* cnt) {
    int i = blockIdx.x * blockDim.x + threadIdx.x;
    if (i < VSEG) cnt[i] = 0u;
}

// ------- stats: moments of inputs + segment histogram + per-point rank -------
// acc layout: [0..9] = sum x_k ; [10..64] = sum x_k*x_l (k<=l), idx = 10 + k*(21-k)/2 + (l-k)
__global__ __launch_bounds__(STATS_B) void stats_partial_k(const float* __restrict__ in,
                                                           const int* __restrict__ idx, int n,
                                                           float* __restrict__ partial,
                                                           unsigned* __restrict__ cnt,
                                                           unsigned* __restrict__ rank) {
    float acc[65];
#pragma unroll
    for (int q = 0; q < 65; ++q) acc[q] = 0.0f;

    for (int i = blockIdx.x * blockDim.x + threadIdx.x; i < n; i += gridDim.x * blockDim.x) {
        const float* ip = in + (size_t)i * KIN;
        float x[KIN];
#pragma unroll
        for (int k = 0; k < KIN; ++k) x[k] = ip[k];
#pragma unroll
        for (int k = 0; k < KIN; ++k) acc[k] += x[k];
#pragma unroll
        for (int k = 0; k < KIN; ++k) {
#pragma unroll
            for (int l = k; l < KIN; ++l)
                acc[10 + k * (21 - k) / 2 + (l - k)] += x[k] * x[l];
        }
        rank[i] = atomicAdd(&cnt[idx[i]], 1u);
    }

    __shared__ float red[STATS_B / 64][65];
    int lane = threadIdx.x & 63, wid = threadIdx.x >> 6;
#pragma unroll
    for (int q = 0; q < 65; ++q) {
        float v = acc[q];
#pragma unroll
        for (int off = 32; off > 0; off >>= 1) v += __shfl_down(v, off, 64);
        if (lane == 0) red[wid][q] = v;
    }
    __syncthreads();
    if (threadIdx.x < 65) {
        float s = 0.0f;
#pragma unroll
        for (int w = 0; w < STATS_B / 64; ++w) s += red[w][threadIdx.x];
        partial[blockIdx.x * 65 + threadIdx.x] = s;
    }
}

// finalize: per-channel BN scale/shift for both branches.
// ss layout: [0..31]=scale_v [32..63]=shift_v [64..95]=scale_u [96..127]=shift_u
__global__ __launch_bounds__(128) void stats_finalize_k(
    const float* __restrict__ partial, int nb, int n,
    const float* __restrict__ Wlin, const float* __restrict__ blin,
    const float* __restrict__ g1, const float* __restrict__ be1,
    const float* __restrict__ Ww1, const float* __restrict__ bw1,
    const float* __restrict__ g2, const float* __restrict__ be2,
    float* __restrict__ ss) {
    __shared__ double tot[65];
    int t = threadIdx.x;
    if (t < 65) {
        double s = 0.0;
        for (int b = 0; b < nb; ++b) s += (double)partial[b * 65 + t];
        tot[t] = s;
    }
    __syncthreads();
    if (t < 64) {
        int c = t & 31;
        const float* W = (t < 32) ? Wlin : Ww1;
        double bb = (double)((t < 32) ? blin[c] : bw1[c]);
        double g  = (double)((t < 32) ? g1[c] : g2[c]);
        double be = (double)((t < 32) ? be1[c] : be2[c]);
        double eps = (t < 32) ? 1e-3 : 1e-5;
        double invN = 1.0 / (double)n;
        double m0 = 0.0;
        for (int k = 0; k < KIN; ++k) m0 += tot[k] * (double)W[k * CH + c];
        m0 *= invN;
        double q0 = 0.0;
        for (int k = 0; k < KIN; ++k)
            for (int l = k; l < KIN; ++l) {
                int qi = 10 + k * (21 - k) / 2 + (l - k);
                double coef = (k == l) ? 1.0 : 2.0;
                q0 += coef * tot[qi] * (double)W[k * CH + c] * (double)W[l * CH + c];
            }
        q0 *= invN;
        double var = q0 - m0 * m0;
        double mean = m0 + bb;
        double sc = g / sqrt(var + eps);
        float scale = (float)sc;
        float shift = (float)(be - mean * sc);
        if (t < 32) { ss[c] = scale; ss[32 + c] = shift; }
        else        { ss[64 + c] = scale; ss[96 + c] = shift; }
    }
}

// ------------------- hierarchical exclusive prefix scan ----------------------
__global__ __launch_bounds__(256) void scan1_k(const unsigned* __restrict__ cnt,
                                               unsigned* __restrict__ segstart,
                                               unsigned* __restrict__ bsum) {
    int t = threadIdx.x;
    int i = blockIdx.x * SCAN_B + t;
    unsigned v = (i < VSEG) ? cnt[i] : 0u;
    int lane = t & 63, w = t >> 6;
    unsigned incl = v;
#pragma unroll
    for (int off = 1; off < 64; off <<= 1) {
        unsigned s = __shfl_up(incl, off, 64);
        if (lane >= off) incl += s;
    }
    __shared__ unsigned wsum[4];
    if (lane == 63) wsum[w] = incl;
    __syncthreads();
    unsigned wo = 0;
#pragma unroll
    for (int k = 0; k < 4; ++k) wo += (k < w) ? wsum[k] : 0u;
    if (i < VSEG) segstart[i] = wo + incl - v;     // block-local exclusive
    if (t == SCAN_B - 1) bsum[blockIdx.x] = wo + incl;
}

__global__ __launch_bounds__(256) void scan2_k(unsigned* __restrict__ bsum, int nb) {
    int t = threadIdx.x;
    unsigned v = (t < nb) ? bsum[t] : 0u;
    int lane = t & 63, w = t >> 6;
    unsigned incl = v;
#pragma unroll
    for (int off = 1; off < 64; off <<= 1) {
        unsigned s = __shfl_up(incl, off, 64);
        if (lane >= off) incl += s;
    }
    __shared__ unsigned wsum[4];
    if (lane == 63) wsum[w] = incl;
    __syncthreads();
    unsigned wo = 0;
#pragma unroll
    for (int k = 0; k < 4; ++k) wo += (k < w) ? wsum[k] : 0u;
    if (t < nb) bsum[t] = wo + incl - v;           // exclusive, in place
}

__global__ __launch_bounds__(256) void scan3_k(unsigned* __restrict__ segstart,
                                               const unsigned* __restrict__ bsum) {
    int i = blockIdx.x * SCAN_B + threadIdx.x;
    if (i < VSEG) segstart[i] += bsum[blockIdx.x];
}

// --- point pass A: out[:, :32], weight[N], atomic-free scatter of indices ----
__global__ __launch_bounds__(256) void passA_k(
    const float* __restrict__ in, const int* __restrict__ idx, int n,
    const float* __restrict__ Wlin, const float* __restrict__ blin,
    const float* __restrict__ Ww1, const float* __restrict__ bw1,
    const float* __restrict__ Ww2, const float* __restrict__ bw2,
    const float* __restrict__ ss,
    const unsigned* __restrict__ segstart, const unsigned* __restrict__ rank,
    float* __restrict__ out, float* __restrict__ weight,
    int* __restrict__ sortedIdx) {
    __shared__ float sWlin[KIN * CH], sWw1[KIN * CH];
    __shared__ float sblin[CH], sbw1[CH], sWw2[CH], sss[128];
    __shared__ float sbw2;
    for (int i = threadIdx.x; i < KIN * CH; i += blockDim.x) { sWlin[i] = Wlin[i]; sWw1[i] = Ww1[i]; }
    for (int i = threadIdx.x; i < CH; i += blockDim.x) { sblin[i] = blin[i]; sbw1[i] = bw1[i]; sWw2[i] = Ww2[i]; }
    for (int i = threadIdx.x; i < 128; i += blockDim.x) sss[i] = ss[i];
    if (threadIdx.x == 0) sbw2 = bw2[0];
    __syncthreads();

    int nidx = blockIdx.x * blockDim.x + threadIdx.x;
    if (nidx >= n) return;

    const float* ip = in + (size_t)nidx * KIN;
    float x[KIN];
#pragma unroll
    for (int k = 0; k < KIN; ++k) x[k] = ip[k];

    float v[CH], u[CH];
#pragma unroll
    for (int c = 0; c < CH; ++c) { v[c] = sblin[c]; u[c] = sbw1[c]; }
#pragma unroll
    for (int k = 0; k < KIN; ++k) {
        float f = x[k];
#pragma unroll
        for (int c = 0; c < CH; ++c) {
            v[c] = fmaf(f, sWlin[k * CH + c], v[c]);
            u[c] = fmaf(f, sWw1[k * CH + c], u[c]);
        }
    }

    float w = sbw2;
#pragma unroll
    for (int c = 0; c < CH; ++c) {
        float hu = fmaxf(fmaf(u[c], sss[64 + c], sss[96 + c]), 0.0f);
        w = fmaf(hu, sWw2[c], w);
    }
    // x_out = relu(norm_v), in place over v
#pragma unroll
    for (int c = 0; c < CH; ++c)
        v[c] = fmaxf(fmaf(v[c], sss[c], sss[32 + c]), 0.0f);

    float4* op = (float4*)(out + (size_t)nidx * 64);
#pragma unroll
    for (int c8 = 0; c8 < 8; ++c8)
        op[c8] = make_float4(v[4 * c8], v[4 * c8 + 1], v[4 * c8 + 2], v[4 * c8 + 3]);

    weight[nidx] = w;
    unsigned p = segstart[idx[nidx]] + rank[nidx];   // no atomics
    sortedIdx[p] = nidx;
}

// ---------------- segmented reduction: one wave per segment ------------------
// lane = c + 32*h; lane handles channel c, points h, h+2, h+4, ...
// softmax without max-shift: e = exp(w) (shift-invariant ratio, w is O(1))
__global__ __launch_bounds__(256) void reduce_k(
    const float* __restrict__ in, const int* __restrict__ sortedIdx,
    const unsigned* __restrict__ segstart, const unsigned* __restrict__ cnt,
    const float* __restrict__ weight,
    const float* __restrict__ Wlin, const float* __restrict__ blin,
    const float* __restrict__ ss,
    float* __restrict__ qmaxf, float* __restrict__ minf,
    float* __restrict__ segsum, float* __restrict__ denomf) {
    __shared__ float sWlin[KIN * CH], sblin[CH], sss[64];
    for (int i = threadIdx.x; i < KIN * CH; i += blockDim.x) sWlin[i] = Wlin[i];
    for (int i = threadIdx.x; i < CH; i += blockDim.x) sblin[i] = blin[i];
    for (int i = threadIdx.x; i < 64; i += blockDim.x) sss[i] = ss[i];
    __syncthreads();

    int lane = threadIdx.x & 63;
    int c = lane & 31, h = lane >> 5;
    int wavesPerBlock = blockDim.x >> 6;
    int gw = blockIdx.x * wavesPerBlock + (threadIdx.x >> 6);
    int nW = gridDim.x * wavesPerBlock;

    float scale = sss[c], shift = sss[32 + c], bl = sblin[c];

    for (int seg = gw; seg < VSEG; seg += nW) {
        int m = (int)cnt[seg];
        size_t ob = (size_t)seg * CH + c;
        if (m == 0) {
            if (h == 0) { qmaxf[ob] = 0.0f; minf[ob] = 0.0f; segsum[ob] = 0.0f; }
            if (lane == 0) denomf[seg] = 0.0f;
            continue;
        }
        int base = (int)segstart[seg];

        float qm = 0.0f;                 // max relu(nv); >=0 for nonempty
        float mn = INFINITY;             // min nv
        float d = 0.0f, S = 0.0f;

        for (int p = h; p < m; p += 2) {
            int pi = sortedIdx[base + p];
            const float* ip = in + (size_t)pi * KIN;
            float v = bl;
#pragma unroll
            for (int k = 0; k < KIN; ++k) v = fmaf(ip[k], sWlin[k * CH + c], v);
            float nv = fmaf(v, scale, shift);
            qm = fmaxf(qm, fmaxf(nv, 0.0f));
            mn = fminf(mn, nv);
            float e = __expf(weight[pi]);
            d += e;
            S = fmaf(e, v, S);
        }

        // merge the two halves (h=0 and h=1); empty half: qm=0, mn=+inf, d=S=0
        qm = fmaxf(qm, __shfl_xor(qm, 32));
        mn = fminf(mn, __shfl_xor(mn, 32));
        d += __shfl_xor(d, 32);
        S += __shfl_xor(S, 32);

        if (h == 0) { qmaxf[ob] = qm; minf[ob] = mn; segsum[ob] = S; }
        if (lane == 0) denomf[seg] = d;
    }
}

// ------------------------------- segment pass --------------------------------
__global__ __launch_bounds__(256) void pass4_k(
    const float* __restrict__ qmaxf, const float* __restrict__ minf,
    const unsigned* __restrict__ cnt, const float* __restrict__ denomf,
    const float* __restrict__ segsum,
    const float* __restrict__ Wfc1, const float* __restrict__ bfc1,
    const float* __restrict__ Wfc2, const float* __restrict__ bfc2,
    float* __restrict__ finalf) {
    __shared__ float sW1[CH * 64], sW2[64 * CH], sb1[64], sb2[CH];
    for (int i = threadIdx.x; i < CH * 64; i += blockDim.x) { sW1[i] = Wfc1[i]; sW2[i] = Wfc2[i]; }
    for (int i = threadIdx.x; i < 64; i += blockDim.x) sb1[i] = bfc1[i];
    for (int i = threadIdx.x; i < CH; i += blockDim.x) sb2[i] = bfc2[i];
    __syncthreads();

    int s = blockIdx.x * blockDim.x + threadIdx.x;
    if (s >= VSEG) return;

    float a1[64];
#pragma unroll
    for (int j = 0; j < 64; ++j) a1[j] = sb1[j];
#pragma unroll 4
    for (int c = 0; c < CH; ++c) {
        float f = minf[(size_t)s * CH + c];
#pragma unroll
        for (int j = 0; j < 64; ++j) a1[j] = fmaf(f, sW1[c * 64 + j], a1[j]);
    }
#pragma unroll
    for (int j = 0; j < 64; ++j) a1[j] = fmaxf(a1[j], 0.0f);

    float dn = fmaxf(denomf[s], 1e-16f);
    float ct = fmaxf((float)cnt[s], 1.0f);
    float inv_dc = 1.0f / (dn * ct);

    for (int c = 0; c < CH; ++c) {
        float z = sb2[c];
#pragma unroll
        for (int j = 0; j < 64; ++j) z = fmaf(a1[j], sW2[j * CH + c], z);
        float cw = 1.0f / (1.0f + expf(-z));
        float qm = qmaxf[(size_t)s * CH + c];
        float wx = segsum[(size_t)s * CH + c] * inv_dc;
        finalf[(size_t)s * CH + c] = cw * qm + (1.0f - cw) * wx;
    }
}

// ------------------------------- gather pass ---------------------------------
__global__ __launch_bounds__(256) void pass5_k(const int* __restrict__ idx, int n,
                                               const float* __restrict__ finalf,
                                               float* __restrict__ out) {
    int nidx = blockIdx.x * blockDim.x + threadIdx.x;
    if (nidx >= n) return;
    int seg = idx[nidx];
    const float4* fp = (const float4*)(finalf + (size_t)seg * CH);
    float4* op = (float4*)(out + (size_t)nidx * 64 + 32);
#pragma unroll
    for (int i = 0; i < 8; ++i) op[i] = fp[i];
}

// ------------------------------- launcher ------------------------------------
extern "C" void kernel_launch(void* const* d_in, const int* in_sizes, int n_in,
                              void* d_out, int out_size, void* d_ws, size_t ws_size,
                              hipStream_t stream) {
    const float* inputs = (const float*)d_in[0];
    const int*   unq    = (const int*)d_in[1];
    const float* Wlin = (const float*)d_in[3];
    const float* blin = (const float*)d_in[4];
    const float* g1   = (const float*)d_in[5];
    const float* be1  = (const float*)d_in[6];
    const float* Ww1  = (const float*)d_in[7];
    const float* bw1  = (const float*)d_in[8];
    const float* g2   = (const float*)d_in[9];
    const float* be2  = (const float*)d_in[10];
    const float* Ww2  = (const float*)d_in[11];
    const float* bw2  = (const float*)d_in[12];
    const float* Wfc1 = (const float*)d_in[13];
    const float* bfc1 = (const float*)d_in[14];
    const float* Wfc2 = (const float*)d_in[15];
    const float* bfc2 = (const float*)d_in[16];

    const int N = in_sizes[0] / KIN;
    float* out = (float*)d_out;

    char* ws = (char*)d_ws;
    size_t off = 0;
    auto alloc = [&](size_t bytes) -> void* {
        void* p = ws + off;
        off += (bytes + 255) & ~(size_t)255;
        return p;
    };
    float*    qmaxf  = (float*)   alloc((size_t)VSEG * CH * 4);
    float*    minf   = (float*)   alloc((size_t)VSEG * CH * 4);
    float*    segsum = (float*)   alloc((size_t)VSEG * CH * 4);
    float*    finalf = (float*)   alloc((size_t)VSEG * CH * 4);
    float*    denomf = (float*)   alloc((size_t)VSEG * 4);
    unsigned* cnt    = (unsigned*)alloc((size_t)VSEG * 4);
    unsigned* segstart=(unsigned*)alloc((size_t)VSEG * 4);
    unsigned* bsum   = (unsigned*)alloc((size_t)NBLK_SCAN * 4);
    float*    ssbuf  = (float*)   alloc(128 * 4);
    float*    partial= (float*)   alloc((size_t)NB_STATS * 65 * 4);
    unsigned* rank   = (unsigned*)alloc((size_t)N * 4);
    float*    weight = (float*)   alloc((size_t)N * 4);
    int*      sortedIdx = (int*)  alloc((size_t)N * 4);

    const int B = 256;
    int g_pt  = (N + B - 1) / B;
    int g_seg = (VSEG + B - 1) / B;
    int g_red = (VSEG + 3) / 4;   // 4 waves/block, 1 wave per segment

    init_cnt_k<<<g_seg, B, 0, stream>>>(cnt);
    stats_partial_k<<<NB_STATS, STATS_B, 0, stream>>>(inputs, unq, N, partial, cnt, rank);
    stats_finalize_k<<<1, 128, 0, stream>>>(partial, NB_STATS, N,
                                            Wlin, blin, g1, be1, Ww1, bw1, g2, be2, ssbuf);
    scan1_k<<<NBLK_SCAN, SCAN_B, 0, stream>>>(cnt, segstart, bsum);
    scan2_k<<<1, SCAN_B, 0, stream>>>(bsum, NBLK_SCAN);
    scan3_k<<<NBLK_SCAN, SCAN_B, 0, stream>>>(segstart, bsum);
    passA_k<<<g_pt, B, 0, stream>>>(inputs, unq, N, Wlin, blin, Ww1, bw1, Ww2, bw2,
                                    ssbuf, segstart, rank, out, weight, sortedIdx);
    reduce_k<<<g_red, B, 0, stream>>>(inputs, sortedIdx, segstart, cnt, weight,
                                      Wlin, blin, ssbuf, qmaxf, minf, segsum, denomf);
    pass4_k<<<g_seg, B, 0, stream>>>(qmaxf, minf, cnt, denomf, segsum,
                                     Wfc1, bfc1, Wfc2, bfc2, finalf);
    pass5_k<<<g_pt, B, 0, stream>>>(unq, N, finalf, out);
}

// Round 6
// 683.332 us; speedup vs baseline: 1.0645x; 1.0645x over previous
//
#include <hip/hip_runtime.h>
#include <math.h>

#define VSEG 50000
#define CH 32
#define KIN 10
#define NB_STATS 512
#define STATS_B 256
#define SCAN_B 256
#define NBLK_SCAN ((VSEG + SCAN_B - 1) / SCAN_B)   // 196

// ---------------------------- init workspace --------------------------------
__global__ __launch_bounds__(256) void init_cnt_k(unsigned* cnt) {
    int i = blockIdx.x * blockDim.x + threadIdx.x;
    if (i < VSEG) cnt[i] = 0u;
}

// ------- stats: moments of inputs + segment histogram + per-point rank -------
// acc layout: [0..9] = sum x_k ; [10..64] = sum x_k*x_l (k<=l), idx = 10 + k*(21-k)/2 + (l-k)
__global__ __launch_bounds__(STATS_B) void stats_partial_k(const float* __restrict__ in,
                                                           const int* __restrict__ idx, int n,
                                                           float* __restrict__ partial,
                                                           unsigned* __restrict__ cnt,
                                                           unsigned* __restrict__ rank) {
    float acc[65];
#pragma unroll
    for (int q = 0; q < 65; ++q) acc[q] = 0.0f;

    for (int i = blockIdx.x * blockDim.x + threadIdx.x; i < n; i += gridDim.x * blockDim.x) {
        const float* ip = in + (size_t)i * KIN;
        float x[KIN];
#pragma unroll
        for (int k = 0; k < KIN; ++k) x[k] = ip[k];
#pragma unroll
        for (int k = 0; k < KIN; ++k) acc[k] += x[k];
#pragma unroll
        for (int k = 0; k < KIN; ++k) {
#pragma unroll
            for (int l = k; l < KIN; ++l)
                acc[10 + k * (21 - k) / 2 + (l - k)] += x[k] * x[l];
        }
        rank[i] = atomicAdd(&cnt[idx[i]], 1u);
    }

    __shared__ float red[STATS_B / 64][65];
    int lane = threadIdx.x & 63, wid = threadIdx.x >> 6;
#pragma unroll
    for (int q = 0; q < 65; ++q) {
        float v = acc[q];
#pragma unroll
        for (int off = 32; off > 0; off >>= 1) v += __shfl_down(v, off, 64);
        if (lane == 0) red[wid][q] = v;
    }
    __syncthreads();
    if (threadIdx.x < 65) {
        float s = 0.0f;
#pragma unroll
        for (int w = 0; w < STATS_B / 64; ++w) s += red[w][threadIdx.x];
        partial[blockIdx.x * 65 + threadIdx.x] = s;
    }
}

// finalize: per-channel BN scale/shift for both branches.
// ss layout: [0..31]=scale_v [32..63]=shift_v [64..95]=scale_u [96..127]=shift_u
__global__ __launch_bounds__(128) void stats_finalize_k(
    const float* __restrict__ partial, int nb, int n,
    const float* __restrict__ Wlin, const float* __restrict__ blin,
    const float* __restrict__ g1, const float* __restrict__ be1,
    const float* __restrict__ Ww1, const float* __restrict__ bw1,
    const float* __restrict__ g2, const float* __restrict__ be2,
    float* __restrict__ ss) {
    __shared__ double tot[65];
    int t = threadIdx.x;
    if (t < 65) {
        double s = 0.0;
        for (int b = 0; b < nb; ++b) s += (double)partial[b * 65 + t];
        tot[t] = s;
    }
    __syncthreads();
    if (t < 64) {
        int c = t & 31;
        const float* W = (t < 32) ? Wlin : Ww1;
        double bb = (double)((t < 32) ? blin[c] : bw1[c]);
        double g  = (double)((t < 32) ? g1[c] : g2[c]);
        double be = (double)((t < 32) ? be1[c] : be2[c]);
        double eps = (t < 32) ? 1e-3 : 1e-5;
        double invN = 1.0 / (double)n;
        double m0 = 0.0;
        for (int k = 0; k < KIN; ++k) m0 += tot[k] * (double)W[k * CH + c];
        m0 *= invN;
        double q0 = 0.0;
        for (int k = 0; k < KIN; ++k)
            for (int l = k; l < KIN; ++l) {
                int qi = 10 + k * (21 - k) / 2 + (l - k);
                double coef = (k == l) ? 1.0 : 2.0;
                q0 += coef * tot[qi] * (double)W[k * CH + c] * (double)W[l * CH + c];
            }
        q0 *= invN;
        double var = q0 - m0 * m0;
        double mean = m0 + bb;
        double sc = g / sqrt(var + eps);
        float scale = (float)sc;
        float shift = (float)(be - mean * sc);
        if (t < 32) { ss[c] = scale; ss[32 + c] = shift; }
        else        { ss[64 + c] = scale; ss[96 + c] = shift; }
    }
}

// ------------------- hierarchical exclusive prefix scan ----------------------
__global__ __launch_bounds__(256) void scan1_k(const unsigned* __restrict__ cnt,
                                               unsigned* __restrict__ segstart,
                                               unsigned* __restrict__ bsum) {
    int t = threadIdx.x;
    int i = blockIdx.x * SCAN_B + t;
    unsigned v = (i < VSEG) ? cnt[i] : 0u;
    int lane = t & 63, w = t >> 6;
    unsigned incl = v;
#pragma unroll
    for (int off = 1; off < 64; off <<= 1) {
        unsigned s = __shfl_up(incl, off, 64);
        if (lane >= off) incl += s;
    }
    __shared__ unsigned wsum[4];
    if (lane == 63) wsum[w] = incl;
    __syncthreads();
    unsigned wo = 0;
#pragma unroll
    for (int k = 0; k < 4; ++k) wo += (k < w) ? wsum[k] : 0u;
    if (i < VSEG) segstart[i] = wo + incl - v;     // block-local exclusive
    if (t == SCAN_B - 1) bsum[blockIdx.x] = wo + incl;
}

__global__ __launch_bounds__(256) void scan2_k(unsigned* __restrict__ bsum, int nb) {
    int t = threadIdx.x;
    unsigned v = (t < nb) ? bsum[t] : 0u;
    int lane = t & 63, w = t >> 6;
    unsigned incl = v;
#pragma unroll
    for (int off = 1; off < 64; off <<= 1) {
        unsigned s = __shfl_up(incl, off, 64);
        if (lane >= off) incl += s;
    }
    __shared__ unsigned wsum[4];
    if (lane == 63) wsum[w] = incl;
    __syncthreads();
    unsigned wo = 0;
#pragma unroll
    for (int k = 0; k < 4; ++k) wo += (k < w) ? wsum[k] : 0u;
    if (t < nb) bsum[t] = wo + incl - v;           // exclusive, in place
}

__global__ __launch_bounds__(256) void scan3_k(unsigned* __restrict__ segstart,
                                               const unsigned* __restrict__ bsum) {
    int i = blockIdx.x * SCAN_B + threadIdx.x;
    if (i < VSEG) segstart[i] += bsum[blockIdx.x];
}

// --------------- scatter: atomic-free, rank precomputed in stats -------------
__global__ __launch_bounds__(256) void scatter_k(const int* __restrict__ idx, int n,
                                                 const unsigned* __restrict__ segstart,
                                                 const unsigned* __restrict__ rank,
                                                 int* __restrict__ sortedIdx) {
    int i = blockIdx.x * blockDim.x + threadIdx.x;
    if (i < n) sortedIdx[segstart[idx[i]] + rank[i]] = i;
}

// ------- fused point+segment pass: one wave per segment over sorted pts ------
// lane = c + 32*h; half-wave h handles points h, h+2, ... of the segment.
// Per point: v,u (10 FMA each), w via 5-step half-wave shfl reduce,
// out[pi,0:32] coalesced 128B store, accumulate qmax/min/sum(e)/sum(e*v).
__global__ __launch_bounds__(256) void fusedB_k(
    const float* __restrict__ in, const int* __restrict__ sortedIdx,
    const unsigned* __restrict__ segstart, const unsigned* __restrict__ cnt,
    const float* __restrict__ Wlin, const float* __restrict__ blin,
    const float* __restrict__ Ww1, const float* __restrict__ bw1,
    const float* __restrict__ Ww2, const float* __restrict__ bw2,
    const float* __restrict__ ss,
    float* __restrict__ out,
    float* __restrict__ qmaxf, float* __restrict__ minf,
    float* __restrict__ segsum, float* __restrict__ denomf) {
    __shared__ float sWlin[KIN * CH], sWw1[KIN * CH];
    __shared__ float sblin[CH], sbw1[CH], sWw2[CH], sss[128];
    for (int i = threadIdx.x; i < KIN * CH; i += blockDim.x) { sWlin[i] = Wlin[i]; sWw1[i] = Ww1[i]; }
    for (int i = threadIdx.x; i < CH; i += blockDim.x) { sblin[i] = blin[i]; sbw1[i] = bw1[i]; sWw2[i] = Ww2[i]; }
    for (int i = threadIdx.x; i < 128; i += blockDim.x) sss[i] = ss[i];
    __syncthreads();

    int lane = threadIdx.x & 63;
    int c = lane & 31, h = lane >> 5;
    int wavesPerBlock = blockDim.x >> 6;
    int gw = blockIdx.x * wavesPerBlock + (threadIdx.x >> 6);
    int nW = gridDim.x * wavesPerBlock;

    float scale = sss[c], shift = sss[32 + c];
    float scaleU = sss[64 + c], shiftU = sss[96 + c];
    float bl = sblin[c], bu = sbw1[c], w2c = sWw2[c];
    float bw2s = bw2[0];

    for (int seg = gw; seg < VSEG; seg += nW) {
        int m = (int)cnt[seg];
        size_t ob = (size_t)seg * CH + c;
        if (m == 0) {
            if (h == 0) { qmaxf[ob] = 0.0f; minf[ob] = 0.0f; segsum[ob] = 0.0f; }
            if (lane == 0) denomf[seg] = 0.0f;
            continue;
        }
        int base = (int)segstart[seg];

        float qm = 0.0f;                 // max relu(nv); >=0 for nonempty
        float mn = INFINITY;             // min nv
        float d = 0.0f, S = 0.0f;

        for (int p = h; p < m; p += 2) {
            int pi = sortedIdx[base + p];
            const float* ip = in + (size_t)pi * KIN;
            float v = bl, u = bu;
#pragma unroll
            for (int k = 0; k < KIN; ++k) {
                float f = ip[k];
                v = fmaf(f, sWlin[k * CH + c], v);
                u = fmaf(f, sWw1[k * CH + c], u);
            }
            float nv = fmaf(v, scale, shift);
            float x  = fmaxf(nv, 0.0f);
            float hu = fmaxf(fmaf(u, scaleU, shiftU), 0.0f);
            float wc = hu * w2c;
#pragma unroll
            for (int off = 16; off > 0; off >>= 1) wc += __shfl_xor(wc, off, 64);
            float e = __expf(wc + bw2s);          // shift-free softmax numerator
            out[(size_t)pi * 64 + c] = x;          // 128B coalesced per half-wave
            qm = fmaxf(qm, x);
            mn = fminf(mn, nv);
            d += e;
            S = fmaf(e, v, S);
        }

        // merge halves; empty half: qm=0, mn=+inf, d=S=0
        qm = fmaxf(qm, __shfl_xor(qm, 32));
        mn = fminf(mn, __shfl_xor(mn, 32));
        d += __shfl_xor(d, 32);
        S += __shfl_xor(S, 32);

        if (h == 0) { qmaxf[ob] = qm; minf[ob] = mn; segsum[ob] = S; }
        if (lane == 0) denomf[seg] = d;
    }
}

// ------------------------------- segment pass --------------------------------
__global__ __launch_bounds__(256) void pass4_k(
    const float* __restrict__ qmaxf, const float* __restrict__ minf,
    const unsigned* __restrict__ cnt, const float* __restrict__ denomf,
    const float* __restrict__ segsum,
    const float* __restrict__ Wfc1, const float* __restrict__ bfc1,
    const float* __restrict__ Wfc2, const float* __restrict__ bfc2,
    float* __restrict__ finalf) {
    __shared__ float sW1[CH * 64], sW2[64 * CH], sb1[64], sb2[CH];
    for (int i = threadIdx.x; i < CH * 64; i += blockDim.x) { sW1[i] = Wfc1[i]; sW2[i] = Wfc2[i]; }
    for (int i = threadIdx.x; i < 64; i += blockDim.x) sb1[i] = bfc1[i];
    for (int i = threadIdx.x; i < CH; i += blockDim.x) sb2[i] = bfc2[i];
    __syncthreads();

    int s = blockIdx.x * blockDim.x + threadIdx.x;
    if (s >= VSEG) return;

    float a1[64];
#pragma unroll
    for (int j = 0; j < 64; ++j) a1[j] = sb1[j];
#pragma unroll 4
    for (int c = 0; c < CH; ++c) {
        float f = minf[(size_t)s * CH + c];
#pragma unroll
        for (int j = 0; j < 64; ++j) a1[j] = fmaf(f, sW1[c * 64 + j], a1[j]);
    }
#pragma unroll
    for (int j = 0; j < 64; ++j) a1[j] = fmaxf(a1[j], 0.0f);

    float dn = fmaxf(denomf[s], 1e-16f);
    float ct = fmaxf((float)cnt[s], 1.0f);
    float inv_dc = 1.0f / (dn * ct);

    for (int c = 0; c < CH; ++c) {
        float z = sb2[c];
#pragma unroll
        for (int j = 0; j < 64; ++j) z = fmaf(a1[j], sW2[j * CH + c], z);
        float cw = 1.0f / (1.0f + expf(-z));
        float qm = qmaxf[(size_t)s * CH + c];
        float wx = segsum[(size_t)s * CH + c] * inv_dc;
        finalf[(size_t)s * CH + c] = cw * qm + (1.0f - cw) * wx;
    }
}

// ------------------------------- gather pass ---------------------------------
__global__ __launch_bounds__(256) void pass5_k(const int* __restrict__ idx, int n,
                                               const float* __restrict__ finalf,
                                               float* __restrict__ out) {
    int nidx = blockIdx.x * blockDim.x + threadIdx.x;
    if (nidx >= n) return;
    int seg = idx[nidx];
    const float4* fp = (const float4*)(finalf + (size_t)seg * CH);
    float4* op = (float4*)(out + (size_t)nidx * 64 + 32);
#pragma unroll
    for (int i = 0; i < 8; ++i) op[i] = fp[i];
}

// ------------------------------- launcher ------------------------------------
extern "C" void kernel_launch(void* const* d_in, const int* in_sizes, int n_in,
                              void* d_out, int out_size, void* d_ws, size_t ws_size,
                              hipStream_t stream) {
    const float* inputs = (const float*)d_in[0];
    const int*   unq    = (const int*)d_in[1];
    const float* Wlin = (const float*)d_in[3];
    const float* blin = (const float*)d_in[4];
    const float* g1   = (const float*)d_in[5];
    const float* be1  = (const float*)d_in[6];
    const float* Ww1  = (const float*)d_in[7];
    const float* bw1  = (const float*)d_in[8];
    const float* g2   = (const float*)d_in[9];
    const float* be2  = (const float*)d_in[10];
    const float* Ww2  = (const float*)d_in[11];
    const float* bw2  = (const float*)d_in[12];
    const float* Wfc1 = (const float*)d_in[13];
    const float* bfc1 = (const float*)d_in[14];
    const float* Wfc2 = (const float*)d_in[15];
    const float* bfc2 = (const float*)d_in[16];

    const int N = in_sizes[0] / KIN;
    float* out = (float*)d_out;

    char* ws = (char*)d_ws;
    size_t off = 0;
    auto alloc = [&](size_t bytes) -> void* {
        void* p = ws + off;
        off += (bytes + 255) & ~(size_t)255;
        return p;
    };
    float*    qmaxf  = (float*)   alloc((size_t)VSEG * CH * 4);
    float*    minf   = (float*)   alloc((size_t)VSEG * CH * 4);
    float*    segsum = (float*)   alloc((size_t)VSEG * CH * 4);
    float*    finalf = (float*)   alloc((size_t)VSEG * CH * 4);
    float*    denomf = (float*)   alloc((size_t)VSEG * 4);
    unsigned* cnt    = (unsigned*)alloc((size_t)VSEG * 4);
    unsigned* segstart=(unsigned*)alloc((size_t)VSEG * 4);
    unsigned* bsum   = (unsigned*)alloc((size_t)NBLK_SCAN * 4);
    float*    ssbuf  = (float*)   alloc(128 * 4);
    float*    partial= (float*)   alloc((size_t)NB_STATS * 65 * 4);
    unsigned* rank   = (unsigned*)alloc((size_t)N * 4);
    int*      sortedIdx = (int*)  alloc((size_t)N * 4);

    const int B = 256;
    int g_pt  = (N + B - 1) / B;
    int g_seg = (VSEG + B - 1) / B;
    int g_red = (VSEG + 3) / 4;   // 4 waves/block, 1 wave per segment

    init_cnt_k<<<g_seg, B, 0, stream>>>(cnt);
    stats_partial_k<<<NB_STATS, STATS_B, 0, stream>>>(inputs, unq, N, partial, cnt, rank);
    stats_finalize_k<<<1, 128, 0, stream>>>(partial, NB_STATS, N,
                                            Wlin, blin, g1, be1, Ww1, bw1, g2, be2, ssbuf);
    scan1_k<<<NBLK_SCAN, SCAN_B, 0, stream>>>(cnt, segstart, bsum);
    scan2_k<<<1, SCAN_B, 0, stream>>>(bsum, NBLK_SCAN);
    scan3_k<<<NBLK_SCAN, SCAN_B, 0, stream>>>(segstart, bsum);
    scatter_k<<<g_pt, B, 0, stream>>>(unq, N, segstart, rank, sortedIdx);
    fusedB_k<<<g_red, B, 0, stream>>>(inputs, sortedIdx, segstart, cnt,
                                      Wlin, blin, Ww1, bw1, Ww2, bw2, ssbuf,
                                      out, qmaxf, minf, segsum, denomf);
    pass4_k<<<g_seg, B, 0, stream>>>(qmaxf, minf, cnt, denomf, segsum,
                                     Wfc1, bfc1, Wfc2, bfc2, finalf);
    pass5_k<<<g_pt, B, 0, stream>>>(unq, N, finalf, out);
}

// Round 7
// 630.957 us; speedup vs baseline: 1.1529x; 1.0830x over previous
//
#include <hip/hip_runtime.h>
#include <math.h>

#define VSEG 50000
#define CH 32
#define KIN 10
#define NB_STATS 512
#define STATS_B 256
#define SCAN_B 256
#define NBLK_SCAN ((VSEG + SCAN_B - 1) / SCAN_B)   // 196
#define SEGS_PER_BLOCK 4

// ---------------------------- init workspace --------------------------------
__global__ __launch_bounds__(256) void init_cnt_k(unsigned* cnt) {
    int i = blockIdx.x * blockDim.x + threadIdx.x;
    if (i < VSEG) cnt[i] = 0u;
}

// ------- stats: moments of inputs + segment histogram + per-point rank -------
// acc layout: [0..9] = sum x_k ; [10..64] = sum x_k*x_l (k<=l), idx = 10 + k*(21-k)/2 + (l-k)
__global__ __launch_bounds__(STATS_B) void stats_partial_k(const float* __restrict__ in,
                                                           const int* __restrict__ idx, int n,
                                                           float* __restrict__ partial,
                                                           unsigned* __restrict__ cnt,
                                                           unsigned* __restrict__ rank) {
    float acc[65];
#pragma unroll
    for (int q = 0; q < 65; ++q) acc[q] = 0.0f;

    for (int i = blockIdx.x * blockDim.x + threadIdx.x; i < n; i += gridDim.x * blockDim.x) {
        const float* ip = in + (size_t)i * KIN;
        float x[KIN];
#pragma unroll
        for (int k = 0; k < KIN; ++k) x[k] = ip[k];
#pragma unroll
        for (int k = 0; k < KIN; ++k) acc[k] += x[k];
#pragma unroll
        for (int k = 0; k < KIN; ++k) {
#pragma unroll
            for (int l = k; l < KIN; ++l)
                acc[10 + k * (21 - k) / 2 + (l - k)] += x[k] * x[l];
        }
        rank[i] = atomicAdd(&cnt[idx[i]], 1u);
    }

    __shared__ float red[STATS_B / 64][65];
    int lane = threadIdx.x & 63, wid = threadIdx.x >> 6;
#pragma unroll
    for (int q = 0; q < 65; ++q) {
        float v = acc[q];
#pragma unroll
        for (int off = 32; off > 0; off >>= 1) v += __shfl_down(v, off, 64);
        if (lane == 0) red[wid][q] = v;
    }
    __syncthreads();
    if (threadIdx.x < 65) {
        float s = 0.0f;
#pragma unroll
        for (int w = 0; w < STATS_B / 64; ++w) s += red[w][threadIdx.x];
        partial[blockIdx.x * 65 + threadIdx.x] = s;
    }
}

// finalize: per-channel BN scale/shift for both branches.
// ss layout: [0..31]=scale_v [32..63]=shift_v [64..95]=scale_u [96..127]=shift_u
__global__ __launch_bounds__(128) void stats_finalize_k(
    const float* __restrict__ partial, int nb, int n,
    const float* __restrict__ Wlin, const float* __restrict__ blin,
    const float* __restrict__ g1, const float* __restrict__ be1,
    const float* __restrict__ Ww1, const float* __restrict__ bw1,
    const float* __restrict__ g2, const float* __restrict__ be2,
    float* __restrict__ ss) {
    __shared__ double tot[65];
    int t = threadIdx.x;
    if (t < 65) {
        double s = 0.0;
        for (int b = 0; b < nb; ++b) s += (double)partial[b * 65 + t];
        tot[t] = s;
    }
    __syncthreads();
    if (t < 64) {
        int c = t & 31;
        const float* W = (t < 32) ? Wlin : Ww1;
        double bb = (double)((t < 32) ? blin[c] : bw1[c]);
        double g  = (double)((t < 32) ? g1[c] : g2[c]);
        double be = (double)((t < 32) ? be1[c] : be2[c]);
        double eps = (t < 32) ? 1e-3 : 1e-5;
        double invN = 1.0 / (double)n;
        double m0 = 0.0;
        for (int k = 0; k < KIN; ++k) m0 += tot[k] * (double)W[k * CH + c];
        m0 *= invN;
        double q0 = 0.0;
        for (int k = 0; k < KIN; ++k)
            for (int l = k; l < KIN; ++l) {
                int qi = 10 + k * (21 - k) / 2 + (l - k);
                double coef = (k == l) ? 1.0 : 2.0;
                q0 += coef * tot[qi] * (double)W[k * CH + c] * (double)W[l * CH + c];
            }
        q0 *= invN;
        double var = q0 - m0 * m0;
        double mean = m0 + bb;
        double sc = g / sqrt(var + eps);
        float scale = (float)sc;
        float shift = (float)(be - mean * sc);
        if (t < 32) { ss[c] = scale; ss[32 + c] = shift; }
        else        { ss[64 + c] = scale; ss[96 + c] = shift; }
    }
}

// ------------------- hierarchical exclusive prefix scan ----------------------
__global__ __launch_bounds__(256) void scan1_k(const unsigned* __restrict__ cnt,
                                               unsigned* __restrict__ segstart,
                                               unsigned* __restrict__ bsum) {
    int t = threadIdx.x;
    int i = blockIdx.x * SCAN_B + t;
    unsigned v = (i < VSEG) ? cnt[i] : 0u;
    int lane = t & 63, w = t >> 6;
    unsigned incl = v;
#pragma unroll
    for (int off = 1; off < 64; off <<= 1) {
        unsigned s = __shfl_up(incl, off, 64);
        if (lane >= off) incl += s;
    }
    __shared__ unsigned wsum[4];
    if (lane == 63) wsum[w] = incl;
    __syncthreads();
    unsigned wo = 0;
#pragma unroll
    for (int k = 0; k < 4; ++k) wo += (k < w) ? wsum[k] : 0u;
    if (i < VSEG) segstart[i] = wo + incl - v;     // block-local exclusive
    if (t == SCAN_B - 1) bsum[blockIdx.x] = wo + incl;
}

__global__ __launch_bounds__(256) void scan2_k(unsigned* __restrict__ bsum, int nb) {
    int t = threadIdx.x;
    unsigned v = (t < nb) ? bsum[t] : 0u;
    int lane = t & 63, w = t >> 6;
    unsigned incl = v;
#pragma unroll
    for (int off = 1; off < 64; off <<= 1) {
        unsigned s = __shfl_up(incl, off, 64);
        if (lane >= off) incl += s;
    }
    __shared__ unsigned wsum[4];
    if (lane == 63) wsum[w] = incl;
    __syncthreads();
    unsigned wo = 0;
#pragma unroll
    for (int k = 0; k < 4; ++k) wo += (k < w) ? wsum[k] : 0u;
    if (t < nb) bsum[t] = wo + incl - v;           // exclusive, in place
}

__global__ __launch_bounds__(256) void scan3_k(unsigned* __restrict__ segstart,
                                               const unsigned* __restrict__ bsum) {
    int i = blockIdx.x * SCAN_B + threadIdx.x;
    if (i < VSEG) segstart[i] += bsum[blockIdx.x];
}

// ---- scatterW: per-point weight w (thread-local) + atomic-free scatter ------
__global__ __launch_bounds__(256) void scatterW_k(
    const float* __restrict__ in, const int* __restrict__ idx, int n,
    const float* __restrict__ Ww1, const float* __restrict__ bw1,
    const float* __restrict__ Ww2, const float* __restrict__ bw2,
    const float* __restrict__ ss,
    const unsigned* __restrict__ segstart, const unsigned* __restrict__ rank,
    int* __restrict__ sortedIdx, float* __restrict__ wsorted) {
    __shared__ float sWw1[KIN * CH], sbw1[CH], sWw2[CH], sssU[64];
    __shared__ float sbw2;
    for (int i = threadIdx.x; i < KIN * CH; i += blockDim.x) sWw1[i] = Ww1[i];
    for (int i = threadIdx.x; i < CH; i += blockDim.x) { sbw1[i] = bw1[i]; sWw2[i] = Ww2[i]; }
    for (int i = threadIdx.x; i < 64; i += blockDim.x) sssU[i] = ss[64 + i];
    if (threadIdx.x == 0) sbw2 = bw2[0];
    __syncthreads();

    int i = blockIdx.x * blockDim.x + threadIdx.x;
    if (i >= n) return;

    const float* ip = in + (size_t)i * KIN;
    float x[KIN];
#pragma unroll
    for (int k = 0; k < KIN; ++k) x[k] = ip[k];

    float w = sbw2;
#pragma unroll 4
    for (int c = 0; c < CH; ++c) {
        float u = sbw1[c];
#pragma unroll
        for (int k = 0; k < KIN; ++k) u = fmaf(x[k], sWw1[k * CH + c], u);
        float hu = fmaxf(fmaf(u, sssU[c], sssU[32 + c]), 0.0f);
        w = fmaf(hu, sWw2[c], w);
    }

    unsigned p = segstart[idx[i]] + rank[i];   // unique slot, no atomics
    sortedIdx[p] = i;
    wsorted[p] = w;
}

// -- mega: per-segment reduce + in-LDS attention MLP + both out halves --------
// block = SEGS_PER_BLOCK segments, one wave each; lane = c + 32*h.
__global__ __launch_bounds__(256) void mega_k(
    const float* __restrict__ in, const int* __restrict__ sortedIdx,
    const float* __restrict__ wsorted,
    const unsigned* __restrict__ segstart, const unsigned* __restrict__ cnt,
    const float* __restrict__ Wlin, const float* __restrict__ blin,
    const float* __restrict__ ss,
    const float* __restrict__ Wfc1, const float* __restrict__ bfc1,
    const float* __restrict__ Wfc2, const float* __restrict__ bfc2,
    float* __restrict__ out) {
    __shared__ float sWlin[KIN * CH], sblin[CH], sssV[64];
    __shared__ float sW1[CH * 64], sb1[64], sW2[64 * CH], sb2[CH];
    __shared__ float qmL[SEGS_PER_BLOCK][CH], mnL[SEGS_PER_BLOCK][CH];
    __shared__ float SL[SEGS_PER_BLOCK][CH], dL[SEGS_PER_BLOCK];
    __shared__ float a1L[SEGS_PER_BLOCK][64], ffL[SEGS_PER_BLOCK][CH];
    __shared__ int mS[SEGS_PER_BLOCK];

    for (int i = threadIdx.x; i < KIN * CH; i += blockDim.x) sWlin[i] = Wlin[i];
    for (int i = threadIdx.x; i < CH; i += blockDim.x) { sblin[i] = blin[i]; sb2[i] = bfc2[i]; }
    for (int i = threadIdx.x; i < 64; i += blockDim.x) { sssV[i] = ss[i]; sb1[i] = bfc1[i]; }
    for (int i = threadIdx.x; i < CH * 64; i += blockDim.x) { sW1[i] = Wfc1[i]; sW2[i] = Wfc2[i]; }
    __syncthreads();

    int lane = threadIdx.x & 63, wid = threadIdx.x >> 6;
    int c = lane & 31, h = lane >> 5;
    int seg = blockIdx.x * SEGS_PER_BLOCK + wid;

    int m = 0; unsigned base = 0;
    if (seg < VSEG) { m = (int)cnt[seg]; base = segstart[seg]; }
    if (lane == 0) mS[wid] = m;

    float scale = sssV[c], shift = sssV[32 + c], bl = sblin[c];
    float qm = 0.0f, mn = INFINITY, d = 0.0f, S = 0.0f;

    // phase 1: gather rows, compute v -> x, write out[:, :32], accumulate
    for (int p = h; p < m; p += 2) {
        int pi = sortedIdx[base + p];
        const float* ip = in + (size_t)pi * KIN;
        float v = bl;
#pragma unroll
        for (int k = 0; k < KIN; ++k) v = fmaf(ip[k], sWlin[k * CH + c], v);
        float nv = fmaf(v, scale, shift);
        float x  = fmaxf(nv, 0.0f);
        out[(size_t)pi * 64 + c] = x;              // 128B half-line, merges with phase 3
        float e = __expf(wsorted[base + p]);        // shift-free softmax numerator
        qm = fmaxf(qm, x);
        mn = fminf(mn, nv);
        d += e;
        S = fmaf(e, v, S);
    }
    qm = fmaxf(qm, __shfl_xor(qm, 32));
    mn = fminf(mn, __shfl_xor(mn, 32));
    d += __shfl_xor(d, 32);
    S += __shfl_xor(S, 32);
    if (h == 0) {
        qmL[wid][c] = qm;
        mnL[wid][c] = (m > 0) ? mn : 0.0f;          // finite_or_zero for empty
        SL[wid][c]  = S;
    }
    if (lane == 0) dL[wid] = d;
    __syncthreads();

    // phase 2a: hidden layer a1[j] = relu(b1[j] + sum_c min[c]*W1[c][j])
    {
        int sl = threadIdx.x >> 6, j = threadIdx.x & 63;
        float a = sb1[j];
#pragma unroll 8
        for (int cc = 0; cc < CH; ++cc) a = fmaf(mnL[sl][cc], sW1[cc * 64 + j], a);
        a1L[sl][j] = fmaxf(a, 0.0f);
    }
    __syncthreads();

    // phase 2b: output layer -> sigmoid -> final_feat, in LDS
    if (threadIdx.x < SEGS_PER_BLOCK * CH) {
        int sl = threadIdx.x >> 5, cc = threadIdx.x & 31;
        float z = sb2[cc];
#pragma unroll 8
        for (int j = 0; j < 64; ++j) z = fmaf(a1L[sl][j], sW2[j * CH + cc], z);
        float cw = 1.0f / (1.0f + __expf(-z));
        float dn = fmaxf(dL[sl], 1e-16f);
        float ct = fmaxf((float)mS[sl], 1.0f);
        float wx = SL[sl][cc] / (dn * ct);
        ffL[sl][cc] = cw * qmL[sl][cc] + (1.0f - cw) * wx;
    }
    __syncthreads();

    // phase 3: broadcast final_feat to all the segment's points (other half-line)
    float ff = ffL[wid][c];
    for (int p = h; p < m; p += 2) {
        int pi = sortedIdx[base + p];
        out[(size_t)pi * 64 + 32 + c] = ff;
    }
}

// ------------------------------- launcher ------------------------------------
extern "C" void kernel_launch(void* const* d_in, const int* in_sizes, int n_in,
                              void* d_out, int out_size, void* d_ws, size_t ws_size,
                              hipStream_t stream) {
    const float* inputs = (const float*)d_in[0];
    const int*   unq    = (const int*)d_in[1];
    const float* Wlin = (const float*)d_in[3];
    const float* blin = (const float*)d_in[4];
    const float* g1   = (const float*)d_in[5];
    const float* be1  = (const float*)d_in[6];
    const float* Ww1  = (const float*)d_in[7];
    const float* bw1  = (const float*)d_in[8];
    const float* g2   = (const float*)d_in[9];
    const float* be2  = (const float*)d_in[10];
    const float* Ww2  = (const float*)d_in[11];
    const float* bw2  = (const float*)d_in[12];
    const float* Wfc1 = (const float*)d_in[13];
    const float* bfc1 = (const float*)d_in[14];
    const float* Wfc2 = (const float*)d_in[15];
    const float* bfc2 = (const float*)d_in[16];

    const int N = in_sizes[0] / KIN;
    float* out = (float*)d_out;

    char* ws = (char*)d_ws;
    size_t off = 0;
    auto alloc = [&](size_t bytes) -> void* {
        void* p = ws + off;
        off += (bytes + 255) & ~(size_t)255;
        return p;
    };
    unsigned* cnt      = (unsigned*)alloc((size_t)VSEG * 4);
    unsigned* segstart = (unsigned*)alloc((size_t)VSEG * 4);
    unsigned* bsum     = (unsigned*)alloc((size_t)NBLK_SCAN * 4);
    float*    ssbuf    = (float*)   alloc(128 * 4);
    float*    partial  = (float*)   alloc((size_t)NB_STATS * 65 * 4);
    unsigned* rank     = (unsigned*)alloc((size_t)N * 4);
    int*      sortedIdx= (int*)     alloc((size_t)N * 4);
    float*    wsorted  = (float*)   alloc((size_t)N * 4);

    const int B = 256;
    int g_pt   = (N + B - 1) / B;
    int g_seg  = (VSEG + B - 1) / B;
    int g_mega = (VSEG + SEGS_PER_BLOCK - 1) / SEGS_PER_BLOCK;

    init_cnt_k<<<g_seg, B, 0, stream>>>(cnt);
    stats_partial_k<<<NB_STATS, STATS_B, 0, stream>>>(inputs, unq, N, partial, cnt, rank);
    stats_finalize_k<<<1, 128, 0, stream>>>(partial, NB_STATS, N,
                                            Wlin, blin, g1, be1, Ww1, bw1, g2, be2, ssbuf);
    scan1_k<<<NBLK_SCAN, SCAN_B, 0, stream>>>(cnt, segstart, bsum);
    scan2_k<<<1, SCAN_B, 0, stream>>>(bsum, NBLK_SCAN);
    scan3_k<<<NBLK_SCAN, SCAN_B, 0, stream>>>(segstart, bsum);
    scatterW_k<<<g_pt, B, 0, stream>>>(inputs, unq, N, Ww1, bw1, Ww2, bw2, ssbuf,
                                       segstart, rank, sortedIdx, wsorted);
    mega_k<<<g_mega, B, 0, stream>>>(inputs, sortedIdx, wsorted, segstart, cnt,
                                     Wlin, blin, ssbuf, Wfc1, bfc1, Wfc2, bfc2, out);
}

// Round 8
// 525.892 us; speedup vs baseline: 1.3832x; 1.1998x over previous
//
#include <hip/hip_runtime.h>
#include <math.h>

#define VSEG 50000
#define CH 32
#define KIN 10
#define NB_STATS 512
#define STATS_B 256
#define SCAN_B 256
#define NBLK_SCAN ((VSEG + SCAN_B - 1) / SCAN_B)   // 196
#define SEGS_PER_BLOCK 4

// ---------------------------- init workspace --------------------------------
__global__ __launch_bounds__(256) void init_cnt_k(unsigned* cnt) {
    int i = blockIdx.x * blockDim.x + threadIdx.x;
    if (i < VSEG) cnt[i] = 0u;
}

// ------- stats: moments of inputs + segment histogram + per-point rank -------
// acc layout: [0..9] = sum x_k ; [10..64] = sum x_k*x_l (k<=l), idx = 10 + k*(21-k)/2 + (l-k)
__global__ __launch_bounds__(STATS_B) void stats_partial_k(const float* __restrict__ in,
                                                           const int* __restrict__ idx, int n,
                                                           float* __restrict__ partial,
                                                           unsigned* __restrict__ cnt,
                                                           unsigned* __restrict__ rank) {
    float acc[65];
#pragma unroll
    for (int q = 0; q < 65; ++q) acc[q] = 0.0f;

    for (int i = blockIdx.x * blockDim.x + threadIdx.x; i < n; i += gridDim.x * blockDim.x) {
        const float* ip = in + (size_t)i * KIN;
        float x[KIN];
#pragma unroll
        for (int k = 0; k < KIN; ++k) x[k] = ip[k];
#pragma unroll
        for (int k = 0; k < KIN; ++k) acc[k] += x[k];
#pragma unroll
        for (int k = 0; k < KIN; ++k) {
#pragma unroll
            for (int l = k; l < KIN; ++l)
                acc[10 + k * (21 - k) / 2 + (l - k)] += x[k] * x[l];
        }
        rank[i] = atomicAdd(&cnt[idx[i]], 1u);
    }

    __shared__ float red[STATS_B / 64][65];
    int lane = threadIdx.x & 63, wid = threadIdx.x >> 6;
#pragma unroll
    for (int q = 0; q < 65; ++q) {
        float v = acc[q];
#pragma unroll
        for (int off = 32; off > 0; off >>= 1) v += __shfl_down(v, off, 64);
        if (lane == 0) red[wid][q] = v;
    }
    __syncthreads();
    if (threadIdx.x < 65) {
        float s = 0.0f;
#pragma unroll
        for (int w = 0; w < STATS_B / 64; ++w) s += red[w][threadIdx.x];
        partial[blockIdx.x * 65 + threadIdx.x] = s;
    }
}

// finalize: per-channel BN scale/shift for both branches.
// ss layout: [0..31]=scale_v [32..63]=shift_v [64..95]=scale_u [96..127]=shift_u
__global__ __launch_bounds__(128) void stats_finalize_k(
    const float* __restrict__ partial, int nb, int n,
    const float* __restrict__ Wlin, const float* __restrict__ blin,
    const float* __restrict__ g1, const float* __restrict__ be1,
    const float* __restrict__ Ww1, const float* __restrict__ bw1,
    const float* __restrict__ g2, const float* __restrict__ be2,
    float* __restrict__ ss) {
    __shared__ double tot[65];
    int t = threadIdx.x;
    if (t < 65) {
        double s = 0.0;
        for (int b = 0; b < nb; ++b) s += (double)partial[b * 65 + t];
        tot[t] = s;
    }
    __syncthreads();
    if (t < 64) {
        int c = t & 31;
        const float* W = (t < 32) ? Wlin : Ww1;
        double bb = (double)((t < 32) ? blin[c] : bw1[c]);
        double g  = (double)((t < 32) ? g1[c] : g2[c]);
        double be = (double)((t < 32) ? be1[c] : be2[c]);
        double eps = (t < 32) ? 1e-3 : 1e-5;
        double invN = 1.0 / (double)n;
        double m0 = 0.0;
        for (int k = 0; k < KIN; ++k) m0 += tot[k] * (double)W[k * CH + c];
        m0 *= invN;
        double q0 = 0.0;
        for (int k = 0; k < KIN; ++k)
            for (int l = k; l < KIN; ++l) {
                int qi = 10 + k * (21 - k) / 2 + (l - k);
                double coef = (k == l) ? 1.0 : 2.0;
                q0 += coef * tot[qi] * (double)W[k * CH + c] * (double)W[l * CH + c];
            }
        q0 *= invN;
        double var = q0 - m0 * m0;
        double mean = m0 + bb;
        double sc = g / sqrt(var + eps);
        float scale = (float)sc;
        float shift = (float)(be - mean * sc);
        if (t < 32) { ss[c] = scale; ss[32 + c] = shift; }
        else        { ss[64 + c] = scale; ss[96 + c] = shift; }
    }
}

// ------------------- hierarchical exclusive prefix scan ----------------------
__global__ __launch_bounds__(256) void scan1_k(const unsigned* __restrict__ cnt,
                                               unsigned* __restrict__ segstart,
                                               unsigned* __restrict__ bsum) {
    int t = threadIdx.x;
    int i = blockIdx.x * SCAN_B + t;
    unsigned v = (i < VSEG) ? cnt[i] : 0u;
    int lane = t & 63, w = t >> 6;
    unsigned incl = v;
#pragma unroll
    for (int off = 1; off < 64; off <<= 1) {
        unsigned s = __shfl_up(incl, off, 64);
        if (lane >= off) incl += s;
    }
    __shared__ unsigned wsum[4];
    if (lane == 63) wsum[w] = incl;
    __syncthreads();
    unsigned wo = 0;
#pragma unroll
    for (int k = 0; k < 4; ++k) wo += (k < w) ? wsum[k] : 0u;
    if (i < VSEG) segstart[i] = wo + incl - v;     // block-local exclusive
    if (t == SCAN_B - 1) bsum[blockIdx.x] = wo + incl;
}

__global__ __launch_bounds__(256) void scan2_k(unsigned* __restrict__ bsum, int nb) {
    int t = threadIdx.x;
    unsigned v = (t < nb) ? bsum[t] : 0u;
    int lane = t & 63, w = t >> 6;
    unsigned incl = v;
#pragma unroll
    for (int off = 1; off < 64; off <<= 1) {
        unsigned s = __shfl_up(incl, off, 64);
        if (lane >= off) incl += s;
    }
    __shared__ unsigned wsum[4];
    if (lane == 63) wsum[w] = incl;
    __syncthreads();
    unsigned wo = 0;
#pragma unroll
    for (int k = 0; k < 4; ++k) wo += (k < w) ? wsum[k] : 0u;
    if (t < nb) bsum[t] = wo + incl - v;           // exclusive, in place
}

__global__ __launch_bounds__(256) void scan3_k(unsigned* __restrict__ segstart,
                                               const unsigned* __restrict__ bsum) {
    int i = blockIdx.x * SCAN_B + threadIdx.x;
    if (i < VSEG) segstart[i] += bsum[blockIdx.x];
}

// ---- scatterW: per-point weight w (thread-local) + packed {pi,w} scatter ----
__global__ __launch_bounds__(256) void scatterW_k(
    const float* __restrict__ in, const int* __restrict__ idx, int n,
    const float* __restrict__ Ww1, const float* __restrict__ bw1,
    const float* __restrict__ Ww2, const float* __restrict__ bw2,
    const float* __restrict__ ss,
    const unsigned* __restrict__ segstart, const unsigned* __restrict__ rank,
    int2* __restrict__ pw) {
    __shared__ float sWw1[KIN * CH], sbw1[CH], sWw2[CH], sssU[64];
    __shared__ float sbw2;
    for (int i = threadIdx.x; i < KIN * CH; i += blockDim.x) sWw1[i] = Ww1[i];
    for (int i = threadIdx.x; i < CH; i += blockDim.x) { sbw1[i] = bw1[i]; sWw2[i] = Ww2[i]; }
    for (int i = threadIdx.x; i < 64; i += blockDim.x) sssU[i] = ss[64 + i];
    if (threadIdx.x == 0) sbw2 = bw2[0];
    __syncthreads();

    int i = blockIdx.x * blockDim.x + threadIdx.x;
    if (i >= n) return;

    const float* ip = in + (size_t)i * KIN;
    float x[KIN];
#pragma unroll
    for (int k = 0; k < KIN; ++k) x[k] = ip[k];

    float w = sbw2;
#pragma unroll 4
    for (int c = 0; c < CH; ++c) {
        float u = sbw1[c];
#pragma unroll
        for (int k = 0; k < KIN; ++k) u = fmaf(x[k], sWw1[k * CH + c], u);
        float hu = fmaxf(fmaf(u, sssU[c], sssU[32 + c]), 0.0f);
        w = fmaf(hu, sWw2[c], w);
    }

    unsigned p = segstart[idx[i]] + rank[i];   // unique slot, no atomics
    pw[p] = make_int2(i, __float_as_int(w));   // single 8B scattered store
}

// -- mega: per-segment reduce + in-LDS attention MLP + both out halves --------
// block = SEGS_PER_BLOCK segments, one wave each; lane = c + 32*h.
// Each half-wave owns a contiguous slot range; 4 points per iteration for MLP.
__global__ __launch_bounds__(256) void mega_k(
    const float* __restrict__ in, const int2* __restrict__ pw,
    const unsigned* __restrict__ segstart, const unsigned* __restrict__ cnt,
    const float* __restrict__ Wlin, const float* __restrict__ blin,
    const float* __restrict__ ss,
    const float* __restrict__ Wfc1, const float* __restrict__ bfc1,
    const float* __restrict__ Wfc2, const float* __restrict__ bfc2,
    float* __restrict__ out) {
    __shared__ float sWlin[KIN * CH], sblin[CH], sssV[64];
    __shared__ float sW1[CH * 64], sb1[64], sW2[64 * CH], sb2[CH];
    __shared__ float qmL[SEGS_PER_BLOCK][CH], mnL[SEGS_PER_BLOCK][CH];
    __shared__ float SL[SEGS_PER_BLOCK][CH], dL[SEGS_PER_BLOCK];
    __shared__ float a1L[SEGS_PER_BLOCK][64], ffL[SEGS_PER_BLOCK][CH];
    __shared__ int mS[SEGS_PER_BLOCK];

    for (int i = threadIdx.x; i < KIN * CH; i += blockDim.x) sWlin[i] = Wlin[i];
    for (int i = threadIdx.x; i < CH; i += blockDim.x) { sblin[i] = blin[i]; sb2[i] = bfc2[i]; }
    for (int i = threadIdx.x; i < 64; i += blockDim.x) { sssV[i] = ss[i]; sb1[i] = bfc1[i]; }
    for (int i = threadIdx.x; i < CH * 64; i += blockDim.x) { sW1[i] = Wfc1[i]; sW2[i] = Wfc2[i]; }
    __syncthreads();

    int lane = threadIdx.x & 63, wid = threadIdx.x >> 6;
    int c = lane & 31, h = lane >> 5;
    int seg = blockIdx.x * SEGS_PER_BLOCK + wid;

    int m = 0; unsigned base = 0;
    if (seg < VSEG) { m = (int)cnt[seg]; base = segstart[seg]; }
    if (lane == 0) mS[wid] = m;

    // contiguous split between the two half-waves
    int mh = (m + 1) >> 1;
    int ps = h ? mh : 0;
    int pe = h ? m : mh;

    float scale = sssV[c], shift = sssV[32 + c], bl = sblin[c];
    float qm = 0.0f, mn = INFINITY, d = 0.0f, S = 0.0f;

    // phase 1: gather rows 4-at-a-time, compute v -> x, write out[:, :32], accumulate
    int p = ps;
    for (; p + 3 < pe; p += 4) {
        int2 q0 = pw[base + p], q1 = pw[base + p + 1];
        int2 q2 = pw[base + p + 2], q3 = pw[base + p + 3];
        const float* ip0 = in + (size_t)q0.x * KIN;
        const float* ip1 = in + (size_t)q1.x * KIN;
        const float* ip2 = in + (size_t)q2.x * KIN;
        const float* ip3 = in + (size_t)q3.x * KIN;
        float r0[KIN], r1[KIN], r2[KIN], r3[KIN];
#pragma unroll
        for (int k = 0; k < KIN; ++k) { r0[k] = ip0[k]; r1[k] = ip1[k]; r2[k] = ip2[k]; r3[k] = ip3[k]; }
        float v0 = bl, v1 = bl, v2 = bl, v3 = bl;
#pragma unroll
        for (int k = 0; k < KIN; ++k) {
            float wk = sWlin[k * CH + c];
            v0 = fmaf(r0[k], wk, v0);
            v1 = fmaf(r1[k], wk, v1);
            v2 = fmaf(r2[k], wk, v2);
            v3 = fmaf(r3[k], wk, v3);
        }
        float nv0 = fmaf(v0, scale, shift), nv1 = fmaf(v1, scale, shift);
        float nv2 = fmaf(v2, scale, shift), nv3 = fmaf(v3, scale, shift);
        float x0 = fmaxf(nv0, 0.0f), x1 = fmaxf(nv1, 0.0f);
        float x2 = fmaxf(nv2, 0.0f), x3 = fmaxf(nv3, 0.0f);
        out[(size_t)q0.x * 64 + c] = x0;
        out[(size_t)q1.x * 64 + c] = x1;
        out[(size_t)q2.x * 64 + c] = x2;
        out[(size_t)q3.x * 64 + c] = x3;
        float e0 = __expf(__int_as_float(q0.y)), e1 = __expf(__int_as_float(q1.y));
        float e2 = __expf(__int_as_float(q2.y)), e3 = __expf(__int_as_float(q3.y));
        qm = fmaxf(fmaxf(fmaxf(qm, x0), fmaxf(x1, x2)), x3);
        mn = fminf(fminf(fminf(mn, nv0), fminf(nv1, nv2)), nv3);
        d += (e0 + e1) + (e2 + e3);
        S = fmaf(e0, v0, S); S = fmaf(e1, v1, S);
        S = fmaf(e2, v2, S); S = fmaf(e3, v3, S);
    }
    for (; p < pe; ++p) {
        int2 q0 = pw[base + p];
        const float* ip0 = in + (size_t)q0.x * KIN;
        float v0 = bl;
#pragma unroll
        for (int k = 0; k < KIN; ++k) v0 = fmaf(ip0[k], sWlin[k * CH + c], v0);
        float nv0 = fmaf(v0, scale, shift);
        float x0 = fmaxf(nv0, 0.0f);
        out[(size_t)q0.x * 64 + c] = x0;
        float e0 = __expf(__int_as_float(q0.y));
        qm = fmaxf(qm, x0);
        mn = fminf(mn, nv0);
        d += e0;
        S = fmaf(e0, v0, S);
    }

    qm = fmaxf(qm, __shfl_xor(qm, 32));
    mn = fminf(mn, __shfl_xor(mn, 32));
    d += __shfl_xor(d, 32);
    S += __shfl_xor(S, 32);
    if (h == 0) {
        qmL[wid][c] = qm;
        mnL[wid][c] = (m > 0) ? mn : 0.0f;          // finite_or_zero for empty
        SL[wid][c]  = S;
    }
    if (lane == 0) dL[wid] = d;
    __syncthreads();

    // phase 2a: hidden layer a1[j] = relu(b1[j] + sum_c min[c]*W1[c][j])
    {
        int sl = threadIdx.x >> 6, j = threadIdx.x & 63;
        float a = sb1[j];
#pragma unroll 8
        for (int cc = 0; cc < CH; ++cc) a = fmaf(mnL[sl][cc], sW1[cc * 64 + j], a);
        a1L[sl][j] = fmaxf(a, 0.0f);
    }
    __syncthreads();

    // phase 2b: output layer -> sigmoid -> final_feat, in LDS
    if (threadIdx.x < SEGS_PER_BLOCK * CH) {
        int sl = threadIdx.x >> 5, cc = threadIdx.x & 31;
        float z = sb2[cc];
#pragma unroll 8
        for (int j = 0; j < 64; ++j) z = fmaf(a1L[sl][j], sW2[j * CH + cc], z);
        float cw = 1.0f / (1.0f + __expf(-z));
        float dn = fmaxf(dL[sl], 1e-16f);
        float ct = fmaxf((float)mS[sl], 1.0f);
        float wx = SL[sl][cc] / (dn * ct);
        ffL[sl][cc] = cw * qmL[sl][cc] + (1.0f - cw) * wx;
    }
    __syncthreads();

    // phase 3: broadcast final_feat to the segment's points (other half-line)
    float ff = ffL[wid][c];
    for (p = ps; p < pe; ++p) {
        int pi = pw[base + p].x;
        out[(size_t)pi * 64 + 32 + c] = ff;
    }
}

// ------------------------------- launcher ------------------------------------
extern "C" void kernel_launch(void* const* d_in, const int* in_sizes, int n_in,
                              void* d_out, int out_size, void* d_ws, size_t ws_size,
                              hipStream_t stream) {
    const float* inputs = (const float*)d_in[0];
    const int*   unq    = (const int*)d_in[1];
    const float* Wlin = (const float*)d_in[3];
    const float* blin = (const float*)d_in[4];
    const float* g1   = (const float*)d_in[5];
    const float* be1  = (const float*)d_in[6];
    const float* Ww1  = (const float*)d_in[7];
    const float* bw1  = (const float*)d_in[8];
    const float* g2   = (const float*)d_in[9];
    const float* be2  = (const float*)d_in[10];
    const float* Ww2  = (const float*)d_in[11];
    const float* bw2  = (const float*)d_in[12];
    const float* Wfc1 = (const float*)d_in[13];
    const float* bfc1 = (const float*)d_in[14];
    const float* Wfc2 = (const float*)d_in[15];
    const float* bfc2 = (const float*)d_in[16];

    const int N = in_sizes[0] / KIN;
    float* out = (float*)d_out;

    char* ws = (char*)d_ws;
    size_t off = 0;
    auto alloc = [&](size_t bytes) -> void* {
        void* p = ws + off;
        off += (bytes + 255) & ~(size_t)255;
        return p;
    };
    unsigned* cnt      = (unsigned*)alloc((size_t)VSEG * 4);
    unsigned* segstart = (unsigned*)alloc((size_t)VSEG * 4);
    unsigned* bsum     = (unsigned*)alloc((size_t)NBLK_SCAN * 4);
    float*    ssbuf    = (float*)   alloc(128 * 4);
    float*    partial  = (float*)   alloc((size_t)NB_STATS * 65 * 4);
    unsigned* rank     = (unsigned*)alloc((size_t)N * 4);
    int2*     pw       = (int2*)    alloc((size_t)N * 8);

    const int B = 256;
    int g_pt   = (N + B - 1) / B;
    int g_seg  = (VSEG + B - 1) / B;
    int g_mega = (VSEG + SEGS_PER_BLOCK - 1) / SEGS_PER_BLOCK;

    init_cnt_k<<<g_seg, B, 0, stream>>>(cnt);
    stats_partial_k<<<NB_STATS, STATS_B, 0, stream>>>(inputs, unq, N, partial, cnt, rank);
    stats_finalize_k<<<1, 128, 0, stream>>>(partial, NB_STATS, N,
                                            Wlin, blin, g1, be1, Ww1, bw1, g2, be2, ssbuf);
    scan1_k<<<NBLK_SCAN, SCAN_B, 0, stream>>>(cnt, segstart, bsum);
    scan2_k<<<1, SCAN_B, 0, stream>>>(bsum, NBLK_SCAN);
    scan3_k<<<NBLK_SCAN, SCAN_B, 0, stream>>>(segstart, bsum);
    scatterW_k<<<g_pt, B, 0, stream>>>(inputs, unq, N, Ww1, bw1, Ww2, bw2, ssbuf,
                                       segstart, rank, pw);
    mega_k<<<g_mega, B, 0, stream>>>(inputs, pw, segstart, cnt,
                                     Wlin, blin, ssbuf, Wfc1, bfc1, Wfc2, bfc2, out);
}